// Round 3
// baseline (270.157 us; speedup 1.0000x reference)
//
#include <hip/hip_runtime.h>
#include <hip/hip_bf16.h>
#include <stdint.h>

#define NE 40000
#define FD 768
#define ED 256
#define NB 32
#define OUTC (NE + 1)

typedef __bf16 bf16x4 __attribute__((ext_vector_type(4)));
typedef __bf16 bf16x8 __attribute__((ext_vector_type(8)));
typedef float f32x4 __attribute__((ext_vector_type(4)));
typedef float f32x16 __attribute__((ext_vector_type(16)));
typedef _Float16 f16x2 __attribute__((ext_vector_type(2)));
typedef _Float16 f16x4 __attribute__((ext_vector_type(4)));

// ws layout: [0,16K) qh f16[32][256] ; [32K,96K) n01_raw fp32[64][256] ;
//            [96K,480K) Wf bf16 fragment-order [8 waves][48 chunks][64 lanes][8]
#define WS_QS 0
#define WS_N01 (32 * 1024)
#define WS_WB (96 * 1024)

__device__ __forceinline__ f16x2 pabs2(f16x2 d) {
    union { f16x2 h; unsigned u; } v; v.h = d; v.u &= 0x7FFF7FFFu; return v.h;
}

// ---------------------------------------------------------------------------
// Kprep: blocks 0..191 convert proj_W fp32->bf16, coalesced read + fragment-
// scatter 8B write. Blocks 192..223: projection with W read ONCE total:
// block pb owns 8 output dims x all 64 slots (2 dots/thread, K=768).
// Fragment f = ((w*48+g)*64+l): value = W[32w + (l&31)][16g + 8*(l>>5) + e]
// ---------------------------------------------------------------------------
__global__ __launch_bounds__(256) void prep_kernel(
    const float* __restrict__ ent_pkl, const float* __restrict__ W,
    const int* __restrict__ ids, const int* __restrict__ mpos,
    __bf16* __restrict__ Wf, float* __restrict__ n01_raw)
{
    const int bid = blockIdx.x;
    const int t = threadIdx.x;

    if (bid < 192) {  // wcvt: linear read, fragment-scatter write
        const int i = bid * 1024 + t * 4;
        const int r = i / FD, c = i - r * FD;
        float4 v = *(const float4*)(W + i);
        __bf16 o[4] = {(__bf16)v.x, (__bf16)v.y, (__bf16)v.z, (__bf16)v.w};
        const int f = ((r >> 5) * 48 + (c >> 4)) * 64 + (r & 31) + ((c >> 3) & 1) * 32;
        *(ushort4*)(Wf + (size_t)f * 8 + (c & 7)) = *(const ushort4*)o;
        return;
    }

    // projection: block pb covers output dims [8*pb, 8*pb+8), all 64 slots
    const int pb = bid - 192;            // 0..31
    const int mp = mpos[0];
    const bool wide = (ids[1] == 0 && ids[3] == 0 && ids[5] == 0);

#pragma unroll
    for (int sub = 0; sub < 2; ++sub) {
        const int id = sub * 256 + t;    // 0..511
        const int o = id & 7;            // local output dim
        const int s = id >> 3;           // slot 0..63
        const int b = s >> 1, sq = s & 1;
        const int col = (sq < mp) ? sq : sq + 1;
        const int flat = b * 3 + col;
        const int idx = wide ? ids[flat * 2] : ids[flat];
        if (!(idx >= 1 && idx <= NE)) continue;  // non-entity handled in qsum

        const f32x4* wr = (const f32x4*)(W + (size_t)(pb * 8 + o) * FD);
        const f32x4* xr = (const f32x4*)(ent_pkl + (size_t)(idx - 1) * FD);
        float a0 = 0.f, a1 = 0.f, a2 = 0.f, a3 = 0.f;
#pragma unroll 4
        for (int k = 0; k < FD / 4; k += 4) {
            f32x4 w0 = wr[k], x0 = xr[k];
            f32x4 w1 = wr[k + 1], x1 = xr[k + 1];
            f32x4 w2 = wr[k + 2], x2 = xr[k + 2];
            f32x4 w3 = wr[k + 3], x3 = xr[k + 3];
            a0 += w0[0]*x0[0] + w0[1]*x0[1] + w0[2]*x0[2] + w0[3]*x0[3];
            a1 += w1[0]*x1[0] + w1[1]*x1[1] + w1[2]*x1[2] + w1[3]*x1[3];
            a2 += w2[0]*x2[0] + w2[1]*x2[1] + w2[2]*x2[2] + w2[3]*x2[3];
            a3 += w3[0]*x3[0] + w3[1]*x3[1] + w3[2]*x3[2] + w3[3]*x3[3];
        }
        n01_raw[s * ED + pb * 8 + o] = (a0 + a1) + (a2 + a3);
    }
}

// ---------------------------------------------------------------------------
// K1b: per-slot normalize, q = sum of 2 normalized rows -> qh (f16), score col 0.
// ---------------------------------------------------------------------------
__global__ __launch_bounds__(256) void qsum_kernel(
    const float* __restrict__ other_emb, const float* __restrict__ n01_raw,
    const int* __restrict__ ids, const int* __restrict__ mpos,
    _Float16* __restrict__ qh, float* __restrict__ out)
{
    __shared__ float red[4];
    __shared__ float nshare;
    const int b = blockIdx.x, t = threadIdx.x;
    const int mp = mpos[0];
    const bool wide = (ids[1] == 0 && ids[3] == 0 && ids[5] == 0);

    float q = 0.f;
#pragma unroll
    for (int s = 0; s < 2; ++s) {
        const int col = (s < mp) ? s : s + 1;
        const int flat = b * 3 + col;
        const int idx = wide ? ids[flat * 2] : ids[flat];
        float v;
        if (idx >= 1 && idx <= NE) v = n01_raw[(b * 2 + s) * ED + t];
        else if (idx == 0) v = other_emb[t];
        else v = other_emb[(size_t)(idx - NE) * ED + t];

        float ss = v * v;
#pragma unroll
        for (int o = 32; o > 0; o >>= 1) ss += __shfl_down(ss, o, 64);
        if ((t & 63) == 0) red[t >> 6] = ss;
        __syncthreads();
        if (t == 0) nshare = fmaxf(sqrtf(red[0] + red[1] + red[2] + red[3]), 1e-12f);
        __syncthreads();
        q += v / nshare;
        __syncthreads();
    }
    qh[b * ED + t] = (_Float16)q;

    float d = fabsf(q - other_emb[t]);
#pragma unroll
    for (int o = 32; o > 0; o >>= 1) d += __shfl_down(d, o, 64);
    if ((t & 63) == 0) red[t >> 6] = d;
    __syncthreads();
    if (t == 0) out[(size_t)b * OUTC] = -(red[0] + red[1] + red[2] + red[3]);
}

// ---------------------------------------------------------------------------
// K2: 625 blocks x 512 thr. Block = 64 entity rows x 256 dims, K=768 in 8
// phases of 96. A reg-staged (3 f32x4/thread), cvt to bf16 ONCE, written to
// fragment-ordered dbuf LDS A[2][6 chunks][2 dh][64 rows][8] (2x12 KB):
// MFMA a-reads are contiguous 512B ds_read_b128, zero conflicts, no cvt in
// the consume loop. Loads for p+1 issue before compute(p) (T14 split); one
// barrier per phase. B from fragment-order Wf, 16B/lane coalesced. C -> Sb
// f16[64][256] granule-swizzled; q table in LDS; NT stores.
// ---------------------------------------------------------------------------
#define SP 256
#define ABUF 12288   // bytes per A phase buffer (64*96*2)

__device__ __forceinline__ void write3(__bf16* B, const int* woff, const f32x4* st) {
#pragma unroll
    for (int j = 0; j < 3; ++j) {
        bf16x4 v;
        v[0] = (__bf16)st[j][0]; v[1] = (__bf16)st[j][1];
        v[2] = (__bf16)st[j][2]; v[3] = (__bf16)st[j][3];
        *(bf16x4*)((char*)B + woff[j]) = v;
    }
}

__global__ __launch_bounds__(512, 6) void gemm_score_kernel(
    const float* __restrict__ ent_pkl, const __bf16* __restrict__ Wf,
    const _Float16* __restrict__ qh, float* __restrict__ out)
{
    __shared__ __align__(16) unsigned char smem[49152];
    __bf16* A0 = (__bf16*)smem;                 // phase buffers (24 KB)
    __bf16* A1 = (__bf16*)(smem + ABUF);
    _Float16* Sb = (_Float16*)smem;             // [64][256] overlay after GEMM
    _Float16* qL = (_Float16*)(smem + 32768);   // [32][256] f16 q table

    const int t = threadIdx.x;
    const int l = t & 63;
    const int w = t >> 6;        // wave 0..7 -> cols 32w..32w+31
    const int m31 = l & 31;
    const int dh = l >> 5;
    const int e0 = blockIdx.x * 64;

    f32x16 acc0, acc1;
#pragma unroll
    for (int i = 0; i < 16; ++i) { acc0[i] = 0.f; acc1[i] = 0.f; }

    // staging geometry: thread = (row = t>>3, seg = t&7), cols seg*12..+11
    const int srow = t >> 3, sseg = t & 7;
    const float* abase = ent_pkl + (size_t)(e0 + srow) * FD + sseg * 12;
    int woff[3];
#pragma unroll
    for (int j = 0; j < 3; ++j) {
        const int k0 = sseg * 12 + 4 * j;
        const int unit = ((k0 >> 4) * 2 + ((k0 >> 3) & 1)) * 64 + srow;
        woff[j] = unit * 16 + (k0 & 7) * 2;
    }

    const __bf16* bp = Wf + (size_t)w * 24576 + (size_t)l * 8;

    f32x4 st[3];
    // prolog: stage phase 0 into A0
    st[0] = *(const f32x4*)(abase + 0);
    st[1] = *(const f32x4*)(abase + 4);
    st[2] = *(const f32x4*)(abase + 8);
    write3(A0, woff, st);
    __syncthreads();

    for (int p = 0; p < 8; ++p) {
        const __bf16* Ab = (p & 1) ? A1 : A0;
        __bf16* An = (p & 1) ? A0 : A1;
        if (p < 7) {   // issue next-phase loads early; hidden under compute
            const float* np = abase + (p + 1) * 96;
            st[0] = *(const f32x4*)(np + 0);
            st[1] = *(const f32x4*)(np + 4);
            st[2] = *(const f32x4*)(np + 8);
        }
        const __bf16* bq = bp + (size_t)p * 6 * 512;
#pragma unroll
        for (int c = 0; c < 6; ++c) {
            bf16x8 bv = *(const bf16x8*)(bq + c * 512);
            const __bf16* fa = Ab + ((c * 2 + dh) * 64 + m31) * 8;
            bf16x8 a0 = *(const bf16x8*)(fa);
            bf16x8 a1 = *(const bf16x8*)(fa + 256);   // +32 rows
            acc0 = __builtin_amdgcn_mfma_f32_32x32x16_bf16(a0, bv, acc0, 0, 0, 0);
            acc1 = __builtin_amdgcn_mfma_f32_32x32x16_bf16(a1, bv, acc1, 0, 0, 0);
        }
        if (p < 7) {
            write3(An, woff, st);   // waitcnt on st auto-inserted here
            __syncthreads();
        }
    }

    // ---- dump C -> Sb f16[64][256]; row=(reg&3)+8*(reg>>2)+4*dh, col=32w+m31,
    //      granule-swizzled: phys granule = (col>>2) ^ (row&15)
    __syncthreads();
    const int colg = 8 * w + (m31 >> 2);
    const int csub = m31 & 3;
#pragma unroll
    for (int r = 0; r < 16; ++r) {
        const int erow = (r & 3) + 8 * (r >> 2) + 4 * dh;
        const int ph = (((colg ^ (erow & 15)) << 2) | csub);
        Sb[erow * SP + ph] = (_Float16)acc0[r];
        Sb[(32 + erow) * SP + ph] = (_Float16)acc1[r];   // (32+erow)&15 == erow&15
    }
    // ---- q table -> LDS (16 KB, 2x 16B per thread) ----
    {
        const uint4* qsrc = (const uint4*)qh;
        uint4* qdst = (uint4*)qL;
        qdst[t] = qsrc[t];
        qdst[t + 512] = qsrc[t + 512];
    }
    __syncthreads();

    // ---- scoring: lane = entity l; wave handles batches 4*wu..4*wu+3 ----
    const int wu = __builtin_amdgcn_readfirstlane(w);
    const f16x4* q0 = (const f16x4*)(qL + (size_t)(4 * wu + 0) * ED);
    const f16x4* q1 = (const f16x4*)(qL + (size_t)(4 * wu + 1) * ED);
    const f16x4* q2 = (const f16x4*)(qL + (size_t)(4 * wu + 2) * ED);
    const f16x4* q3 = (const f16x4*)(qL + (size_t)(4 * wu + 3) * ED);
    const int swl = l & 15;
    const _Float16* xbase = Sb + (size_t)l * SP;

    float s0 = 0.f, s1 = 0.f, s2 = 0.f, s3 = 0.f;
    for (int cb = 0; cb < 8; ++cb) {
        f16x2 t0 = {0, 0}, t1 = {0, 0}, t2 = {0, 0}, t3 = {0, 0};
#pragma unroll
        for (int ci = 0; ci < 8; ++ci) {
            const int c = cb * 8 + ci;
            f16x4 xv = *(const f16x4*)(xbase + ((c ^ swl) << 2));
            f16x2 xlo = __builtin_shufflevector(xv, xv, 0, 1);
            f16x2 xhi = __builtin_shufflevector(xv, xv, 2, 3);
            f16x4 qa = q0[c], qb = q1[c], qc = q2[c], qd = q3[c];
            t0 = t0 + pabs2(__builtin_shufflevector(qa, qa, 0, 1) - xlo);
            t0 = t0 + pabs2(__builtin_shufflevector(qa, qa, 2, 3) - xhi);
            t1 = t1 + pabs2(__builtin_shufflevector(qb, qb, 0, 1) - xlo);
            t1 = t1 + pabs2(__builtin_shufflevector(qb, qb, 2, 3) - xhi);
            t2 = t2 + pabs2(__builtin_shufflevector(qc, qc, 0, 1) - xlo);
            t2 = t2 + pabs2(__builtin_shufflevector(qc, qc, 2, 3) - xhi);
            t3 = t3 + pabs2(__builtin_shufflevector(qd, qd, 0, 1) - xlo);
            t3 = t3 + pabs2(__builtin_shufflevector(qd, qd, 2, 3) - xhi);
        }
        s0 += (float)t0[0] + (float)t0[1];
        s1 += (float)t1[0] + (float)t1[1];
        s2 += (float)t2[0] + (float)t2[1];
        s3 += (float)t3[0] + (float)t3[1];
    }
    float* ob = out + 1 + e0 + l;
    __builtin_nontemporal_store(-s0, ob + (size_t)(4 * wu + 0) * OUTC);
    __builtin_nontemporal_store(-s1, ob + (size_t)(4 * wu + 1) * OUTC);
    __builtin_nontemporal_store(-s2, ob + (size_t)(4 * wu + 2) * OUTC);
    __builtin_nontemporal_store(-s3, ob + (size_t)(4 * wu + 3) * OUTC);
}

extern "C" void kernel_launch(void* const* d_in, const int* in_sizes, int n_in,
                              void* d_out, int out_size, void* d_ws, size_t ws_size,
                              hipStream_t stream) {
    const float* ent_pkl = (const float*)d_in[0];
    const float* other_emb = (const float*)d_in[1];
    const float* proj_W = (const float*)d_in[2];
    const int* ids = (const int*)d_in[3];
    const int* mpos = (const int*)d_in[4];
    float* out = (float*)d_out;

    _Float16* qh = (_Float16*)((char*)d_ws + WS_QS);
    float* n01_raw = (float*)((char*)d_ws + WS_N01);
    __bf16* Wf = (__bf16*)((char*)d_ws + WS_WB);

    prep_kernel<<<224, 256, 0, stream>>>(ent_pkl, proj_W, ids, mpos, Wf, n01_raw);
    qsum_kernel<<<NB, 256, 0, stream>>>(other_emb, n01_raw, ids, mpos, qh, out);
    gemm_score_kernel<<<NE / 64, 512, 0, stream>>>(ent_pkl, Wf, qh, out);
}

// Round 5
// 267.245 us; speedup vs baseline: 1.0109x; 1.0109x over previous
//
#include <hip/hip_runtime.h>
#include <hip/hip_bf16.h>
#include <stdint.h>

#define NE 40000
#define FD 768
#define ED 256
#define NB 32
#define OUTC (NE + 1)

typedef __bf16 bf16x8 __attribute__((ext_vector_type(8)));
typedef float f32x4 __attribute__((ext_vector_type(4)));
typedef float f32x16 __attribute__((ext_vector_type(16)));
typedef _Float16 f16x2 __attribute__((ext_vector_type(2)));
typedef _Float16 f16x4 __attribute__((ext_vector_type(4)));

// ws layout: [0,16K) qh f16[32][256] ; [32K,96K) n01_raw fp32[64][256] ;
//            [96K,480K) Wf bf16 fragment-order [8 waves][48 chunks][64 lanes][8]
#define WS_QS 0
#define WS_N01 (32 * 1024)
#define WS_WB (96 * 1024)

__device__ __forceinline__ f16x2 pabs2(f16x2 d) {
    union { f16x2 h; unsigned u; } v; v.h = d; v.u &= 0x7FFF7FFFu; return v.h;
}

__device__ __forceinline__ bf16x8 cvt8(f32x4 lo, f32x4 hi) {
    bf16x8 v;
    v[0] = (__bf16)lo[0]; v[1] = (__bf16)lo[1]; v[2] = (__bf16)lo[2]; v[3] = (__bf16)lo[3];
    v[4] = (__bf16)hi[0]; v[5] = (__bf16)hi[1]; v[6] = (__bf16)hi[2]; v[7] = (__bf16)hi[3];
    return v;
}

// async global->LDS DMA, 16B/lane, zero VGPR cost; dest = wave-uniform base + lane*16
__device__ __forceinline__ void gload16(const void* g, void* l) {
    __builtin_amdgcn_global_load_lds(
        (const __attribute__((address_space(1))) unsigned int*)g,
        (__attribute__((address_space(3))) unsigned int*)l, 16, 0, 0);
}

// Shared pipeline geometry (gemm + proj): 12 phases x K=64.
// Phase buffer = 64 rows x 16 units(16B each, 4 f32). Unit swizzle (both sides):
//   phys unit(row,g) = row*16 + (g ^ (row&15)); DMA src pre-applies the inverse.
// Conflict-free ds_read_b128: phys%8 = (g&7)^(row&7) is a permutation per 8 rows.

// ---------------------------------------------------------------------------
// Kprep (512 thr): blocks 0..95 wcvt (coalesced read, fragment-scatter write).
// Block 96: projection as ONE MFMA block: A = 64 gathered slot rows (DMA,
// idx-clamped), B built from fp32 W on the fly (independent of Wf -> no race),
// C -> n01_raw fp32[64][256].
// Fragment f = ((w*48+g)*64+l): value = W[32w + (l&31)][16g + 8*(l>>5) + e]
// ---------------------------------------------------------------------------
__global__ __launch_bounds__(512) void prep_kernel(
    const float* __restrict__ ent_pkl, const float* __restrict__ W,
    const int* __restrict__ ids, const int* __restrict__ mpos,
    __bf16* __restrict__ Wf, float* __restrict__ n01_raw)
{
    __shared__ __align__(16) unsigned char smem[65536];
    const int t = threadIdx.x;

    if (blockIdx.x < 96) {  // wcvt
        const int i = blockIdx.x * 2048 + t * 4;
        const int r = i / FD, c = i - r * FD;
        float4 v = *(const float4*)(W + i);
        __bf16 o[4] = {(__bf16)v.x, (__bf16)v.y, (__bf16)v.z, (__bf16)v.w};
        const int f = ((r >> 5) * 48 + (c >> 4)) * 64 + (r & 31) + ((c >> 3) & 1) * 32;
        *(ushort4*)(Wf + (size_t)f * 8 + (c & 7)) = *(const ushort4*)o;
        return;
    }

    // ---- projection block ----
    const int l = t & 63;
    const int w = t >> 6;
    const int m31 = l & 31;
    const int dh = l >> 5;
    const int sw = m31 & 15;
    const int mp = mpos[0];
    const bool wide = (ids[1] == 0 && ids[3] == 0 && ids[5] == 0);

    // DMA geometry: thread t stages units t (row r1) and t+512 (row r1+32)
    const int r1 = t >> 4;
    const int goff = ((t & 15) ^ (r1 & 15)) * 4;  // same for r1 and r1+32
    int rowA, rowB;
    {
        int s = r1;
        int b = s >> 1, sq = s & 1;
        int col = (sq < mp) ? sq : sq + 1;
        int flat = b * 3 + col;
        int idx = wide ? ids[flat * 2] : ids[flat];
        rowA = (idx >= 1 && idx <= NE) ? idx - 1 : 0;
        s = r1 + 32;
        b = s >> 1; sq = s & 1;
        col = (sq < mp) ? sq : sq + 1;
        flat = b * 3 + col;
        idx = wide ? ids[flat * 2] : ids[flat];
        rowB = (idx >= 1 && idx <= NE) ? idx - 1 : 0;
    }
    const float* ab1 = ent_pkl + (size_t)rowA * FD + goff;
    const float* ab2 = ent_pkl + (size_t)rowB * FD + goff;
    const float* Wr = W + (size_t)(32 * w + m31) * FD + 8 * dh;

    f32x16 acc0, acc1;
#pragma unroll
    for (int i = 0; i < 16; ++i) { acc0[i] = 0.f; acc1[i] = 0.f; }

#define P_ISSUE(P) { char* lb = (char*)smem + ((P) & 3) * 16384 + t * 16; \
        gload16(ab1 + (P) * 64, lb); gload16(ab2 + (P) * 64, lb + 8192); }

#define P_PHASE(P, NW, DOISS) \
    asm volatile("s_waitcnt vmcnt(" #NW ")" ::: "memory"); \
    __builtin_amdgcn_s_barrier(); \
    __builtin_amdgcn_sched_barrier(0); \
    { \
        f32x4 wv[8]; \
        _Pragma("unroll") for (int c2 = 0; c2 < 4; ++c2) { \
            wv[2 * c2]     = *(const f32x4*)(Wr + 16 * (4 * (P) + c2)); \
            wv[2 * c2 + 1] = *(const f32x4*)(Wr + 16 * (4 * (P) + c2) + 4); \
        } \
        __builtin_amdgcn_sched_barrier(0); \
        if (DOISS) P_ISSUE((P) + 3); \
        const char* Ab = (const char*)smem + ((P) & 3) * 16384; \
        _Pragma("unroll") for (int c2 = 0; c2 < 4; ++c2) { \
            const int u0 = (4 * c2 + 2 * dh) ^ sw; \
            const char* pa = Ab + (m31 * 16 + u0) * 16; \
            const char* pb = Ab + (m31 * 16 + (u0 ^ 1)) * 16; \
            f32x4 lo0 = *(const f32x4*)pa,          hi0 = *(const f32x4*)pb; \
            f32x4 lo1 = *(const f32x4*)(pa + 8192), hi1 = *(const f32x4*)(pb + 8192); \
            bf16x8 bv = cvt8(wv[2 * c2], wv[2 * c2 + 1]); \
            acc0 = __builtin_amdgcn_mfma_f32_32x32x16_bf16(cvt8(lo0, hi0), bv, acc0, 0, 0, 0); \
            acc1 = __builtin_amdgcn_mfma_f32_32x32x16_bf16(cvt8(lo1, hi1), bv, acc1, 0, 0, 0); \
        } \
    }

    P_ISSUE(0); P_ISSUE(1); P_ISSUE(2);
    P_PHASE(0, 4, 1)  P_PHASE(1, 8, 1)  P_PHASE(2, 8, 1)  P_PHASE(3, 8, 1)
    P_PHASE(4, 8, 1)  P_PHASE(5, 8, 1)  P_PHASE(6, 8, 1)  P_PHASE(7, 8, 1)
    P_PHASE(8, 8, 1)  P_PHASE(9, 8, 0)  P_PHASE(10, 8, 0) P_PHASE(11, 8, 0)

#pragma unroll
    for (int r = 0; r < 16; ++r) {
        const int erow = (r & 3) + 8 * (r >> 2) + 4 * dh;
        n01_raw[erow * ED + 32 * w + m31] = acc0[r];
        n01_raw[(32 + erow) * ED + 32 * w + m31] = acc1[r];
    }
}

// ---------------------------------------------------------------------------
// K1b: per-slot normalize, q = sum of 2 normalized rows -> qh (f16), score col 0.
// ---------------------------------------------------------------------------
__global__ __launch_bounds__(256) void qsum_kernel(
    const float* __restrict__ other_emb, const float* __restrict__ n01_raw,
    const int* __restrict__ ids, const int* __restrict__ mpos,
    _Float16* __restrict__ qh, float* __restrict__ out)
{
    __shared__ float red[4];
    __shared__ float nshare;
    const int b = blockIdx.x, t = threadIdx.x;
    const int mp = mpos[0];
    const bool wide = (ids[1] == 0 && ids[3] == 0 && ids[5] == 0);

    float q = 0.f;
#pragma unroll
    for (int s = 0; s < 2; ++s) {
        const int col = (s < mp) ? s : s + 1;
        const int flat = b * 3 + col;
        const int idx = wide ? ids[flat * 2] : ids[flat];
        float v;
        if (idx >= 1 && idx <= NE) v = n01_raw[(b * 2 + s) * ED + t];
        else if (idx == 0) v = other_emb[t];
        else v = other_emb[(size_t)(idx - NE) * ED + t];

        float ss = v * v;
#pragma unroll
        for (int o = 32; o > 0; o >>= 1) ss += __shfl_down(ss, o, 64);
        if ((t & 63) == 0) red[t >> 6] = ss;
        __syncthreads();
        if (t == 0) nshare = fmaxf(sqrtf(red[0] + red[1] + red[2] + red[3]), 1e-12f);
        __syncthreads();
        q += v / nshare;
        __syncthreads();
    }
    qh[b * ED + t] = (_Float16)q;

    float d = fabsf(q - other_emb[t]);
#pragma unroll
    for (int o = 32; o > 0; o >>= 1) d += __shfl_down(d, o, 64);
    if ((t & 63) == 0) red[t >> 6] = d;
    __syncthreads();
    if (t == 0) out[(size_t)b * OUTC] = -(red[0] + red[1] + red[2] + red[3]);
}

// ---------------------------------------------------------------------------
// K2: 625 blocks x 512 thr. 64 entity rows x 256 dims, K=768 in 12 phases of
// 64. A staged fp32 via global_load_lds into 4 rotating 16KB buffers (both-
// sides swizzle), 3 phases of DMA in flight, counted vmcnt (never 0 mid-loop),
// raw s_barrier + sched_barrier fences. B (Wf fragments) prefetched ONE phase
// ahead and issued BEFORE the DMA (vmcnt is in-order: bv must be older than
// the newest DMA or its use would drain the queue). C -> Sb f16[64][256]
// granule-swizzled; q table in LDS; f16 packed scoring; NT stores.
// ---------------------------------------------------------------------------
#define SP 256

__global__ __launch_bounds__(512, 4) void gemm_score_kernel(
    const float* __restrict__ ent_pkl, const __bf16* __restrict__ Wf,
    const _Float16* __restrict__ qh, float* __restrict__ out)
{
    __shared__ __align__(16) unsigned char smem[65536];
    _Float16* Sb = (_Float16*)smem;             // [64][256] overlay after GEMM
    _Float16* qL = (_Float16*)(smem + 32768);   // [32][256] f16 q table

    const int t = threadIdx.x;
    const int l = t & 63;
    const int w = t >> 6;        // wave 0..7 -> cols 32w..32w+31
    const int m31 = l & 31;
    const int dh = l >> 5;
    const int sw = m31 & 15;
    const int e0 = blockIdx.x * 64;

    f32x16 acc0, acc1;
#pragma unroll
    for (int i = 0; i < 16; ++i) { acc0[i] = 0.f; acc1[i] = 0.f; }

    // DMA: thread t stages units t (row r1) and t+512 (row r1+32)
    const int r1 = t >> 4;
    const int goff = ((t & 15) ^ (r1 & 15)) * 4;
    const float* ab1 = ent_pkl + (size_t)(e0 + r1) * FD + goff;
    const float* ab2 = ent_pkl + (size_t)(e0 + r1 + 32) * FD + goff;
    const __bf16* bp = Wf + (size_t)w * 24576 + (size_t)l * 8;

    bf16x8 bvA[4], bvB[4];

#define G_ISSUE(P) { char* lb = (char*)smem + ((P) & 3) * 16384 + t * 16; \
        gload16(ab1 + (P) * 64, lb); gload16(ab2 + (P) * 64, lb + 8192); }

#define G_PHASE(P, NW, BUSE, BNEXT, DOISS, DOLOAD) \
    asm volatile("s_waitcnt vmcnt(" #NW ")" ::: "memory"); \
    __builtin_amdgcn_s_barrier(); \
    __builtin_amdgcn_sched_barrier(0); \
    if (DOLOAD) { _Pragma("unroll") for (int c2 = 0; c2 < 4; ++c2) \
        BNEXT[c2] = *(const bf16x8*)(bp + (size_t)(4 * ((P) + 1) + c2) * 512); } \
    __builtin_amdgcn_sched_barrier(0); \
    if (DOISS) G_ISSUE((P) + 3); \
    { \
        const char* Ab = (const char*)smem + ((P) & 3) * 16384; \
        _Pragma("unroll") for (int c2 = 0; c2 < 4; ++c2) { \
            const int u0 = (4 * c2 + 2 * dh) ^ sw; \
            const char* pa = Ab + (m31 * 16 + u0) * 16; \
            const char* pb = Ab + (m31 * 16 + (u0 ^ 1)) * 16; \
            f32x4 lo0 = *(const f32x4*)pa,          hi0 = *(const f32x4*)pb; \
            f32x4 lo1 = *(const f32x4*)(pa + 8192), hi1 = *(const f32x4*)(pb + 8192); \
            acc0 = __builtin_amdgcn_mfma_f32_32x32x16_bf16(cvt8(lo0, hi0), BUSE[c2], acc0, 0, 0, 0); \
            acc1 = __builtin_amdgcn_mfma_f32_32x32x16_bf16(cvt8(lo1, hi1), BUSE[c2], acc1, 0, 0, 0); \
        } \
    }

    // prolog: 3 DMA phases + bv(0); order keeps DMA oldest in the vmcnt FIFO
    G_ISSUE(0); G_ISSUE(1); G_ISSUE(2);
#pragma unroll
    for (int c2 = 0; c2 < 4; ++c2) bvA[c2] = *(const bf16x8*)(bp + (size_t)c2 * 512);

    G_PHASE(0, 8, bvA, bvB, 1, 1)   G_PHASE(1, 8, bvB, bvA, 1, 1)
    G_PHASE(2, 8, bvA, bvB, 1, 1)   G_PHASE(3, 8, bvB, bvA, 1, 1)
    G_PHASE(4, 8, bvA, bvB, 1, 1)   G_PHASE(5, 8, bvB, bvA, 1, 1)
    G_PHASE(6, 8, bvA, bvB, 1, 1)   G_PHASE(7, 8, bvB, bvA, 1, 1)
    G_PHASE(8, 8, bvA, bvB, 1, 1)   G_PHASE(9, 8, bvB, bvA, 0, 1)
    G_PHASE(10, 6, bvA, bvB, 0, 1)  G_PHASE(11, 4, bvB, bvA, 0, 0)

    // ---- dump C -> Sb f16[64][256]; row=(reg&3)+8*(reg>>2)+4*dh, col=32w+m31,
    //      granule-swizzled: phys granule = (col>>2) ^ (row&15)
    __syncthreads();
    const int colg = 8 * w + (m31 >> 2);
    const int csub = m31 & 3;
#pragma unroll
    for (int r = 0; r < 16; ++r) {
        const int erow = (r & 3) + 8 * (r >> 2) + 4 * dh;
        const int ph = (((colg ^ (erow & 15)) << 2) | csub);
        Sb[erow * SP + ph] = (_Float16)acc0[r];
        Sb[(32 + erow) * SP + ph] = (_Float16)acc1[r];   // (32+erow)&15 == erow&15
    }
    // ---- q table -> LDS (16 KB, 2x 16B per thread) ----
    {
        const uint4* qsrc = (const uint4*)qh;
        uint4* qdst = (uint4*)qL;
        qdst[t] = qsrc[t];
        qdst[t + 512] = qsrc[t + 512];
    }
    __syncthreads();

    // ---- scoring: lane = entity l; wave handles batches 4*wu..4*wu+3 ----
    const int wu = __builtin_amdgcn_readfirstlane(w);
    const f16x4* q0 = (const f16x4*)(qL + (size_t)(4 * wu + 0) * ED);
    const f16x4* q1 = (const f16x4*)(qL + (size_t)(4 * wu + 1) * ED);
    const f16x4* q2 = (const f16x4*)(qL + (size_t)(4 * wu + 2) * ED);
    const f16x4* q3 = (const f16x4*)(qL + (size_t)(4 * wu + 3) * ED);
    const int swl = l & 15;
    const _Float16* xbase = Sb + (size_t)l * SP;

    float s0 = 0.f, s1 = 0.f, s2 = 0.f, s3 = 0.f;
    for (int cb = 0; cb < 8; ++cb) {
        f16x2 t0 = {0, 0}, t1 = {0, 0}, t2 = {0, 0}, t3 = {0, 0};
#pragma unroll
        for (int ci = 0; ci < 8; ++ci) {
            const int c = cb * 8 + ci;
            f16x4 xv = *(const f16x4*)(xbase + ((c ^ swl) << 2));
            f16x2 xlo = __builtin_shufflevector(xv, xv, 0, 1);
            f16x2 xhi = __builtin_shufflevector(xv, xv, 2, 3);
            f16x4 qa = q0[c], qb = q1[c], qc = q2[c], qd = q3[c];
            t0 = t0 + pabs2(__builtin_shufflevector(qa, qa, 0, 1) - xlo);
            t0 = t0 + pabs2(__builtin_shufflevector(qa, qa, 2, 3) - xhi);
            t1 = t1 + pabs2(__builtin_shufflevector(qb, qb, 0, 1) - xlo);
            t1 = t1 + pabs2(__builtin_shufflevector(qb, qb, 2, 3) - xhi);
            t2 = t2 + pabs2(__builtin_shufflevector(qc, qc, 0, 1) - xlo);
            t2 = t2 + pabs2(__builtin_shufflevector(qc, qc, 2, 3) - xhi);
            t3 = t3 + pabs2(__builtin_shufflevector(qd, qd, 0, 1) - xlo);
            t3 = t3 + pabs2(__builtin_shufflevector(qd, qd, 2, 3) - xhi);
        }
        s0 += (float)t0[0] + (float)t0[1];
        s1 += (float)t1[0] + (float)t1[1];
        s2 += (float)t2[0] + (float)t2[1];
        s3 += (float)t3[0] + (float)t3[1];
    }
    float* ob = out + 1 + e0 + l;
    __builtin_nontemporal_store(-s0, ob + (size_t)(4 * wu + 0) * OUTC);
    __builtin_nontemporal_store(-s1, ob + (size_t)(4 * wu + 1) * OUTC);
    __builtin_nontemporal_store(-s2, ob + (size_t)(4 * wu + 2) * OUTC);
    __builtin_nontemporal_store(-s3, ob + (size_t)(4 * wu + 3) * OUTC);
}

extern "C" void kernel_launch(void* const* d_in, const int* in_sizes, int n_in,
                              void* d_out, int out_size, void* d_ws, size_t ws_size,
                              hipStream_t stream) {
    const float* ent_pkl = (const float*)d_in[0];
    const float* other_emb = (const float*)d_in[1];
    const float* proj_W = (const float*)d_in[2];
    const int* ids = (const int*)d_in[3];
    const int* mpos = (const int*)d_in[4];
    float* out = (float*)d_out;

    _Float16* qh = (_Float16*)((char*)d_ws + WS_QS);
    float* n01_raw = (float*)((char*)d_ws + WS_N01);
    __bf16* Wf = (__bf16*)((char*)d_ws + WS_WB);

    prep_kernel<<<97, 512, 0, stream>>>(ent_pkl, proj_W, ids, mpos, Wf, n01_raw);
    qsum_kernel<<<NB, 256, 0, stream>>>(other_emb, n01_raw, ids, mpos, qh, out);
    gemm_score_kernel<<<NE / 64, 512, 0, stream>>>(ent_pkl, Wf, qh, out);
}

// Round 7
// 237.483 us; speedup vs baseline: 1.1376x; 1.1253x over previous
//
#include <hip/hip_runtime.h>
#include <hip/hip_bf16.h>
#include <stdint.h>

#define NE 40000
#define FD 768
#define ED 256
#define NB 32
#define OUTC (NE + 1)

typedef __bf16 bf16x8 __attribute__((ext_vector_type(8)));
typedef float f32x4 __attribute__((ext_vector_type(4)));
typedef float f32x16 __attribute__((ext_vector_type(16)));
typedef _Float16 f16x2 __attribute__((ext_vector_type(2)));
typedef _Float16 f16x4 __attribute__((ext_vector_type(4)));

// ws layout: [0,16K) qh f16[32][256] ; [96K,480K) Wf bf16 fragment-order
#define WS_QS 0
#define WS_WB (96 * 1024)

__device__ __forceinline__ f16x2 pabs2(f16x2 d) {
    union { f16x2 h; unsigned u; } v; v.h = d; v.u &= 0x7FFF7FFFu; return v.h;
}

__device__ __forceinline__ bf16x8 cvt8(f32x4 lo, f32x4 hi) {
    bf16x8 v;
    v[0] = (__bf16)lo[0]; v[1] = (__bf16)lo[1]; v[2] = (__bf16)lo[2]; v[3] = (__bf16)lo[3];
    v[4] = (__bf16)hi[0]; v[5] = (__bf16)hi[1]; v[6] = (__bf16)hi[2]; v[7] = (__bf16)hi[3];
    return v;
}

// async global->LDS DMA (prep's single projection block only)
__device__ __forceinline__ void gload16(const void* g, void* l) {
    __builtin_amdgcn_global_load_lds(
        (const __attribute__((address_space(1))) unsigned int*)g,
        (__attribute__((address_space(3))) unsigned int*)l, 16, 0, 0);
}

// ---------------------------------------------------------------------------
// Kprep (512 thr): blocks 0..95 wcvt (coalesced read, fragment-scatter write).
// Block 96: projection as ONE MFMA block (12-phase DMA pipeline, K=64/phase),
// then FUSED qsum: fixup non-entity rows, per-slot norms (shfl_xor), q = sum
// of normalized pair -> qh f16, score col 0 -> out. qsum kernel eliminated.
// Fragment f = ((w*48+g)*64+l): value = W[32w + (l&31)][16g + 8*(l>>5) + e]
// ---------------------------------------------------------------------------
__global__ __launch_bounds__(512) void prep_kernel(
    const float* __restrict__ ent_pkl, const float* __restrict__ W,
    const float* __restrict__ other_emb,
    const int* __restrict__ ids, const int* __restrict__ mpos,
    __bf16* __restrict__ Wf, _Float16* __restrict__ qh, float* __restrict__ out)
{
    __shared__ __align__(16) unsigned char smem[65536];
    const int t = threadIdx.x;

    if (blockIdx.x < 96) {  // wcvt
        const int i = blockIdx.x * 2048 + t * 4;
        const int r = i / FD, c = i - r * FD;
        float4 v = *(const float4*)(W + i);
        __bf16 o[4] = {(__bf16)v.x, (__bf16)v.y, (__bf16)v.z, (__bf16)v.w};
        const int f = ((r >> 5) * 48 + (c >> 4)) * 64 + (r & 31) + ((c >> 3) & 1) * 32;
        *(ushort4*)(Wf + (size_t)f * 8 + (c & 7)) = *(const ushort4*)o;
        return;
    }

    // ---- projection block ----
    const int l = t & 63;
    const int w = t >> 6;
    const int m31 = l & 31;
    const int dh = l >> 5;
    const int sw = m31 & 15;
    const int mp = mpos[0];
    const bool wide = (ids[1] == 0 && ids[3] == 0 && ids[5] == 0);

    // DMA geometry: thread t stages units t (row r1) and t+512 (row r1+32)
    const int r1 = t >> 4;
    const int goff = ((t & 15) ^ (r1 & 15)) * 4;  // same for r1 and r1+32
    int rowA, rowB;
    {
        int s = r1;
        int b = s >> 1, sq = s & 1;
        int col = (sq < mp) ? sq : sq + 1;
        int flat = b * 3 + col;
        int idx = wide ? ids[flat * 2] : ids[flat];
        rowA = (idx >= 1 && idx <= NE) ? idx - 1 : 0;
        s = r1 + 32;
        b = s >> 1; sq = s & 1;
        col = (sq < mp) ? sq : sq + 1;
        flat = b * 3 + col;
        idx = wide ? ids[flat * 2] : ids[flat];
        rowB = (idx >= 1 && idx <= NE) ? idx - 1 : 0;
    }
    const float* ab1 = ent_pkl + (size_t)rowA * FD + goff;
    const float* ab2 = ent_pkl + (size_t)rowB * FD + goff;
    const float* Wr = W + (size_t)(32 * w + m31) * FD + 8 * dh;

    f32x16 acc0, acc1;
#pragma unroll
    for (int i = 0; i < 16; ++i) { acc0[i] = 0.f; acc1[i] = 0.f; }

#define P_ISSUE(P) { char* lb = (char*)smem + ((P) & 3) * 16384 + t * 16; \
        gload16(ab1 + (P) * 64, lb); gload16(ab2 + (P) * 64, lb + 8192); }

#define P_PHASE(P, NW, DOISS) \
    asm volatile("s_waitcnt vmcnt(" #NW ")" ::: "memory"); \
    __builtin_amdgcn_s_barrier(); \
    __builtin_amdgcn_sched_barrier(0); \
    { \
        f32x4 wv[8]; \
        _Pragma("unroll") for (int c2 = 0; c2 < 4; ++c2) { \
            wv[2 * c2]     = *(const f32x4*)(Wr + 16 * (4 * (P) + c2)); \
            wv[2 * c2 + 1] = *(const f32x4*)(Wr + 16 * (4 * (P) + c2) + 4); \
        } \
        __builtin_amdgcn_sched_barrier(0); \
        if (DOISS) P_ISSUE((P) + 3); \
        const char* Ab = (const char*)smem + ((P) & 3) * 16384; \
        _Pragma("unroll") for (int c2 = 0; c2 < 4; ++c2) { \
            const int u0 = (4 * c2 + 2 * dh) ^ sw; \
            const char* pa = Ab + (m31 * 16 + u0) * 16; \
            const char* pb = Ab + (m31 * 16 + (u0 ^ 1)) * 16; \
            f32x4 lo0 = *(const f32x4*)pa,          hi0 = *(const f32x4*)pb; \
            f32x4 lo1 = *(const f32x4*)(pa + 8192), hi1 = *(const f32x4*)(pb + 8192); \
            bf16x8 bv = cvt8(wv[2 * c2], wv[2 * c2 + 1]); \
            acc0 = __builtin_amdgcn_mfma_f32_32x32x16_bf16(cvt8(lo0, hi0), bv, acc0, 0, 0, 0); \
            acc1 = __builtin_amdgcn_mfma_f32_32x32x16_bf16(cvt8(lo1, hi1), bv, acc1, 0, 0, 0); \
        } \
    }

    P_ISSUE(0); P_ISSUE(1); P_ISSUE(2);
    P_PHASE(0, 4, 1)  P_PHASE(1, 8, 1)  P_PHASE(2, 8, 1)  P_PHASE(3, 8, 1)
    P_PHASE(4, 8, 1)  P_PHASE(5, 8, 1)  P_PHASE(6, 8, 1)  P_PHASE(7, 8, 1)
    P_PHASE(8, 8, 1)  P_PHASE(9, 8, 0)  P_PHASE(10, 8, 0) P_PHASE(11, 8, 0)

    // ---- dump raw projection -> LDS n01 f32[64][256] (overlay DMA bufs) ----
    float* n01 = (float*)smem;
    __syncthreads();
#pragma unroll
    for (int r = 0; r < 16; ++r) {
        const int erow = (r & 3) + 8 * (r >> 2) + 4 * dh;
        n01[erow * ED + 32 * w + m31] = acc0[r];
        n01[(32 + erow) * ED + 32 * w + m31] = acc1[r];
    }
    __syncthreads();

    // ---- fixup non-entity slots with other_emb rows ----
    {
        const int slot = t >> 3, k = t & 7;
        const int b = slot >> 1, sq = slot & 1;
        const int col = (sq < mp) ? sq : sq + 1;
        const int flat = b * 3 + col;
        const int idx = wide ? ids[flat * 2] : ids[flat];
        if (!(idx >= 1 && idx <= NE)) {
            const float* src = (idx == 0) ? other_emb
                                          : other_emb + (size_t)(idx - NE) * ED;
            for (int d = k * 32; d < k * 32 + 32; ++d) n01[slot * ED + d] = src[d];
        }
    }
    __syncthreads();

    // ---- norms (all 8 lanes of slot-group get sum via shfl_xor) + q + col0 ----
    {
        const int slot = t >> 3, k = t & 7;
        float ss = 0.f;
        const f32x4* v4 = (const f32x4*)(n01 + slot * ED + k * 32);
#pragma unroll
        for (int i = 0; i < 8; ++i) {
            f32x4 v = v4[i];
            ss += v[0] * v[0] + v[1] * v[1] + v[2] * v[2] + v[3] * v[3];
        }
#pragma unroll
        for (int o = 4; o > 0; o >>= 1) ss += __shfl_xor(ss, o, 8);
        const float mynorm = fmaxf(sqrtf(ss), 1e-12f);
        const float otnorm = __shfl_xor(mynorm, 8, 16);
        const float n0 = (t & 8) ? otnorm : mynorm;   // slot 2b
        const float n1 = (t & 8) ? mynorm : otnorm;   // slot 2b+1
        const float i0 = 1.f / n0, i1 = 1.f / n1;

        const int b = t >> 4, dt = t & 15;
        float part = 0.f;
#pragma unroll
        for (int i = 0; i < 16; ++i) {
            const int d = dt * 16 + i;
            float q = n01[(2 * b) * ED + d] * i0 + n01[(2 * b + 1) * ED + d] * i1;
            qh[b * ED + d] = (_Float16)q;
            part += fabsf(q - other_emb[d]);
        }
#pragma unroll
        for (int o = 8; o > 0; o >>= 1) part += __shfl_down(part, o, 16);
        if (dt == 0) out[(size_t)b * OUTC] = -part;
    }
}

// ---------------------------------------------------------------------------
// K2: 625 blocks x 512 thr. 64 entity rows x 256 dims, K=768 in 4 phases of
// 192, per-block phase stagger (blockIdx&3) to desync chip-wide bursts.
// A reg-staged: 6 f32x4/thread prefetch ISSUED SPREAD through the MFMA loop
// (sched_barrier pins; launch_bounds(512,4) gives the 128-VGPR room r3
// lacked), cvt once -> fragment-order dbuf LDS (2x24 KB), 16B ds_write_b128
// and ds_read_b128 both at the wave64 bank floor. One barrier per phase.
// C -> Sb f16[64][256] granule-swizzled; q in LDS; f16 packed scoring; NT out.
// ---------------------------------------------------------------------------
#define SP 256

__global__ __launch_bounds__(512, 4) void gemm_score_kernel(
    const float* __restrict__ ent_pkl, const __bf16* __restrict__ Wf,
    const _Float16* __restrict__ qh, float* __restrict__ out)
{
    __shared__ __align__(16) unsigned char smem[49152];
    __bf16* A0 = (__bf16*)smem;                 // [24 units][64 rows][8] bf16
    __bf16* A1 = (__bf16*)(smem + 24576);
    _Float16* Sb = (_Float16*)smem;             // [64][256] overlay after GEMM
    _Float16* qL = (_Float16*)(smem + 32768);   // [32][256] f16 q table

    const int t = threadIdx.x;
    const int l = t & 63;
    const int w = t >> 6;        // wave 0..7 -> cols 32w..32w+31
    const int m31 = l & 31;
    const int dh = l >> 5;
    const int e0 = blockIdx.x * 64;
    const int ph0 = blockIdx.x & 3;   // phase stagger

    f32x16 acc0, acc1;
#pragma unroll
    for (int i = 0; i < 16; ++i) { acc0[i] = 0.f; acc1[i] = 0.f; }

    // staging geometry: thread = (row=t>>3, seg=t&7); cols seg*24..+23 of phase
    const int srow = t >> 3, sseg = t & 7;
    const float* abase = ent_pkl + (size_t)(e0 + srow) * FD + sseg * 24;
    int woff[3];
#pragma unroll
    for (int j = 0; j < 3; ++j) {
        const int uidx = sseg * 3 + j;               // 8-bf16 unit 0..23
        woff[j] = (uidx * 64 + srow) * 16;           // bytes
    }

    const __bf16* bp = Wf + (size_t)w * 24576 + (size_t)l * 8;

    f32x4 st[6];
    // prolog: stage phase ph0 into A0
    {
        const float* ap = abase + ph0 * 192;
#pragma unroll
        for (int j = 0; j < 6; ++j) st[j] = *(const f32x4*)(ap + 4 * j);
#pragma unroll
        for (int j = 0; j < 3; ++j)
            *(bf16x8*)((char*)A0 + woff[j]) = cvt8(st[2 * j], st[2 * j + 1]);
        __syncthreads();
    }

#pragma unroll
    for (int p = 0; p < 4; ++p) {
        const __bf16* Ab = (p & 1) ? A1 : A0;
        __bf16* An = (p & 1) ? A0 : A1;
        const int kp = (p + ph0) & 3;
        const float* np = abase + (size_t)(((p + 1 + ph0) & 3)) * 192;
        const __bf16* bq = bp + (size_t)kp * 12 * 512;
#pragma unroll
        for (int c = 0; c < 12; ++c) {
            if (p < 3 && (c & 1) == 0) {             // spread prefetch issues
                st[c >> 1] = *(const f32x4*)(np + 4 * (c >> 1));
                __builtin_amdgcn_sched_barrier(0);   // pin: issue HERE, not later
            }
            bf16x8 bv = *(const bf16x8*)(bq + (size_t)c * 512);
            const int u0 = 2 * c + dh;
            const char* pa = (const char*)Ab + (u0 * 64 + m31) * 16;
            bf16x8 a0 = *(const bf16x8*)pa;
            bf16x8 a1 = *(const bf16x8*)(pa + 512);  // rows +32
            acc0 = __builtin_amdgcn_mfma_f32_32x32x16_bf16(a0, bv, acc0, 0, 0, 0);
            acc1 = __builtin_amdgcn_mfma_f32_32x32x16_bf16(a1, bv, acc1, 0, 0, 0);
        }
        if (p < 3) {
#pragma unroll
            for (int j = 0; j < 3; ++j)              // waitcnt lands here (late)
                *(bf16x8*)((char*)An + woff[j]) = cvt8(st[2 * j], st[2 * j + 1]);
            __syncthreads();
        }
    }

    // ---- dump C -> Sb f16[64][256]; row=(reg&3)+8*(reg>>2)+4*dh, col=32w+m31,
    //      granule-swizzled: phys granule = (col>>2) ^ (row&15)
    __syncthreads();
    const int colg = 8 * w + (m31 >> 2);
    const int csub = m31 & 3;
#pragma unroll
    for (int r = 0; r < 16; ++r) {
        const int erow = (r & 3) + 8 * (r >> 2) + 4 * dh;
        const int ph = (((colg ^ (erow & 15)) << 2) | csub);
        Sb[erow * SP + ph] = (_Float16)acc0[r];
        Sb[(32 + erow) * SP + ph] = (_Float16)acc1[r];   // (32+erow)&15 == erow&15
    }
    // ---- q table -> LDS (16 KB, 2x 16B per thread) ----
    {
        const uint4* qsrc = (const uint4*)qh;
        uint4* qdst = (uint4*)qL;
        qdst[t] = qsrc[t];
        qdst[t + 512] = qsrc[t + 512];
    }
    __syncthreads();

    // ---- scoring: lane = entity l; wave handles batches 4*wu..4*wu+3 ----
    const int wu = __builtin_amdgcn_readfirstlane(w);
    const f16x4* q0 = (const f16x4*)(qL + (size_t)(4 * wu + 0) * ED);
    const f16x4* q1 = (const f16x4*)(qL + (size_t)(4 * wu + 1) * ED);
    const f16x4* q2 = (const f16x4*)(qL + (size_t)(4 * wu + 2) * ED);
    const f16x4* q3 = (const f16x4*)(qL + (size_t)(4 * wu + 3) * ED);
    const int swl = l & 15;
    const _Float16* xbase = Sb + (size_t)l * SP;

    float s0 = 0.f, s1 = 0.f, s2 = 0.f, s3 = 0.f;
    for (int cb = 0; cb < 8; ++cb) {
        f16x2 t0 = {0, 0}, t1 = {0, 0}, t2 = {0, 0}, t3 = {0, 0};
#pragma unroll
        for (int ci = 0; ci < 8; ++ci) {
            const int c = cb * 8 + ci;
            f16x4 xv = *(const f16x4*)(xbase + ((c ^ swl) << 2));
            f16x2 xlo = __builtin_shufflevector(xv, xv, 0, 1);
            f16x2 xhi = __builtin_shufflevector(xv, xv, 2, 3);
            f16x4 qa = q0[c], qb = q1[c], qc = q2[c], qd = q3[c];
            t0 = t0 + pabs2(__builtin_shufflevector(qa, qa, 0, 1) - xlo);
            t0 = t0 + pabs2(__builtin_shufflevector(qa, qa, 2, 3) - xhi);
            t1 = t1 + pabs2(__builtin_shufflevector(qb, qb, 0, 1) - xlo);
            t1 = t1 + pabs2(__builtin_shufflevector(qb, qb, 2, 3) - xhi);
            t2 = t2 + pabs2(__builtin_shufflevector(qc, qc, 0, 1) - xlo);
            t2 = t2 + pabs2(__builtin_shufflevector(qc, qc, 2, 3) - xhi);
            t3 = t3 + pabs2(__builtin_shufflevector(qd, qd, 0, 1) - xlo);
            t3 = t3 + pabs2(__builtin_shufflevector(qd, qd, 2, 3) - xhi);
        }
        s0 += (float)t0[0] + (float)t0[1];
        s1 += (float)t1[0] + (float)t1[1];
        s2 += (float)t2[0] + (float)t2[1];
        s3 += (float)t3[0] + (float)t3[1];
    }
    float* ob = out + 1 + e0 + l;
    __builtin_nontemporal_store(-s0, ob + (size_t)(4 * wu + 0) * OUTC);
    __builtin_nontemporal_store(-s1, ob + (size_t)(4 * wu + 1) * OUTC);
    __builtin_nontemporal_store(-s2, ob + (size_t)(4 * wu + 2) * OUTC);
    __builtin_nontemporal_store(-s3, ob + (size_t)(4 * wu + 3) * OUTC);
}

extern "C" void kernel_launch(void* const* d_in, const int* in_sizes, int n_in,
                              void* d_out, int out_size, void* d_ws, size_t ws_size,
                              hipStream_t stream) {
    const float* ent_pkl = (const float*)d_in[0];
    const float* other_emb = (const float*)d_in[1];
    const float* proj_W = (const float*)d_in[2];
    const int* ids = (const int*)d_in[3];
    const int* mpos = (const int*)d_in[4];
    float* out = (float*)d_out;

    _Float16* qh = (_Float16*)((char*)d_ws + WS_QS);
    __bf16* Wf = (__bf16*)((char*)d_ws + WS_WB);

    prep_kernel<<<97, 512, 0, stream>>>(ent_pkl, proj_W, other_emb, ids, mpos, Wf, qh, out);
    gemm_score_kernel<<<NE / 64, 512, 0, stream>>>(ent_pkl, Wf, qh, out);
}